// Round 13
// baseline (83.023 us; speedup 1.0000x reference)
//
#include <hip/hip_runtime.h>
#include <hip/hip_bf16.h>

#define NB   16
#define CINC 64
#define COUTC 64
#define NV   25
#define TLEN 512
#define KK   3
#define TKK  3

typedef short short8 __attribute__((ext_vector_type(8)));
typedef float f32x4  __attribute__((ext_vector_type(4)));
typedef float f32x16 __attribute__((ext_vector_type(16)));

#define XT_ROWS 514        // padded: row 0 = t=-1 (zero), rows 1..512 = t, row 513 = t=512 (zero)
#define XS_STRIDE 17408    // 17 x 1KB stage ops; used bytes = 130*128 = 16640
#define NWT3BLK (NV * 9)   // 225 weight-prep blocks

__device__ __forceinline__ unsigned pack_bf16(float lo, float hi) {
  __hip_bfloat16 l = __float2bfloat16(lo);
  __hip_bfloat16 h = __float2bfloat16(hi);
  unsigned short ul = *reinterpret_cast<unsigned short*>(&l);
  unsigned short uh = *reinterpret_cast<unsigned short*>(&h);
  return (unsigned)ul | ((unsigned)uh << 16);
}

// ================= fused prep: Wt3 (blocks 0..224) + padded xT (rest) ========
__global__ __launch_bounds__(256) void prep_all(
    const float* __restrict__ x, const float* __restrict__ W,
    const unsigned char* __restrict__ mask_raw,
    __hip_bfloat16* __restrict__ Wt3, __hip_bfloat16* __restrict__ xT) {
  __shared__ float ts[64][65];
  int bid = blockIdx.x;
  if (bid < NWT3BLK) {
    int blk = bid;                 // v*9 + k*3 + kt
    int v = blk / 9, kkt = blk % 9, k = kkt / 3, kt = kkt % 3;
    const int* mi = (const int*)mask_raw;
    int ok = 1;
    for (int i = 0; i < 18; ++i) {
      int m = mi[i];
      if (m != 0 && m != 1) ok = 0;
    }
    int m = ok ? mi[v * KK + k] : (int)(mask_raw[v * KK + k] != 0);
    const float* Wv = W + (size_t)v * COUTC * CINC * 9;
    __hip_bfloat16* dst = Wt3 + (size_t)blk * 4096;
    for (int i = threadIdx.x; i < 4096; i += 256) {
      int e     = i & 7;
      int lane  = (i >> 3) & 63;
      int ks    = (i >> 9) & 3;
      int oslab = i >> 11;
      int o = oslab * 32 + (lane & 31);
      int c = ks * 16 + 8 * (lane >> 5) + e;
      float val = m ? Wv[(o * CINC + c) * 9 + k * 3 + kt] : 0.f;
      dst[i] = __float2bfloat16(val);
    }
    return;
  }
  bid -= NWT3BLK;
  const int tb = (bid & 7) * 64;
  const int vn = bid >> 3;
  const int v  = vn % NV;
  const int n  = vn / NV;
  const int tid = threadIdx.x;
  for (int i = tid; i < 1024; i += 256) {
    int c = i >> 4, tq = (i & 15) * 4;
    float4 val = *(const float4*)(x + (((size_t)n * CINC + c) * NV + v) * TLEN + tb + tq);
    ts[c][tq + 0] = val.x;
    ts[c][tq + 1] = val.y;
    ts[c][tq + 2] = val.z;
    ts[c][tq + 3] = val.w;
  }
  __syncthreads();
  unsigned* base = (unsigned*)(xT + ((size_t)(n * NV + v) * XT_ROWS) * CINC);
  for (int i = tid; i < 512; i += 256) {
    int c8 = i & 7, t = i >> 3;   // t in 0..63
    int c0 = c8 * 8;
    uint4 d;
    d.x = pack_bf16(ts[c0 + 0][t], ts[c0 + 1][t]);
    d.y = pack_bf16(ts[c0 + 2][t], ts[c0 + 3][t]);
    d.z = pack_bf16(ts[c0 + 4][t], ts[c0 + 5][t]);
    d.w = pack_bf16(ts[c0 + 6][t], ts[c0 + 7][t]);
    *(uint4*)(base + (size_t)(tb + 1 + t) * 32 + c8 * 4) = d;
  }
  if (tb == 0 && tid < 32) base[tid] = 0u;
  if (tb == TLEN - 64 && tid < 32) base[513 * 32 + tid] = 0u;
}

__device__ __forceinline__ const char* slab_base(const __hip_bfloat16* xT,
                                                 int n, int vk, int tb) {
  return (const char*)xT + ((size_t)(n * NV + vk) * XT_ROWS + tb) * 128;
}

// Main: block = 64 o x 256 t (two 128-t phases), 800 blocks. R12 retried
// SPILL-FREE: per-k A-sets (12 frags / 48 VGPR, <=2 transiently live — the
// exact register profile R10 compiled cleanly), R10's counted-vmcnt ladder
// extended across both phases, A(k+1) always issued one k-phase early.
// Verification gate: WRITE_SIZE must return to ~51.2 MB (no spill stores).
__global__ __launch_bounds__(256, 3) void lcn_mfma32(
    const __hip_bfloat16* __restrict__ xT,
    const __hip_bfloat16* __restrict__ Wt3,
    const float* __restrict__ bias,
    const int* __restrict__ idx,
    float* __restrict__ out) {
  __shared__ char xs[KK][XS_STRIDE];   // 52,224 B
  __shared__ char xs_dummy[1024];      // dummy-op sink (never read)

  const int b  = blockIdx.x;           // 800 = 16 n x 2 tc x 25 v
  const int n  = b & 15;
  const int tc = (b >> 4) & 1;
  const int v  = b >> 5;
  const int tid  = threadIdx.x;
  const int lane = tid & 63;
  const int wave = tid >> 6;
  const int os   = wave & 1;     // this wave's o-slab
  const int th   = wave >> 1;    // this wave's 64-t half (within 128-t phase)
  const int hi   = lane >> 5;
  const int l31  = lane & 31;

#define LOAD_A(DST, KIDX)                                                     \
  {                                                                           \
    const short8* wb = (const short8*)Wt3 +                                   \
        ((size_t)((v * KK + (KIDX)) * TKK) * 2 + os) * 256 + lane;            \
    _Pragma("unroll") for (int kt = 0; kt < TKK; ++kt)                        \
      _Pragma("unroll") for (int ks = 0; ks < 4; ++ks)                        \
        DST[kt * 4 + ks] = wb[kt * 512 + (ks << 6)];                          \
  }

#define STAGE_PHASE(TBP)                                                      \
  {                                                                           \
    const char* gbs[KK] = {                                                   \
        slab_base(xT, n, idx[v * KK + 0], (TBP)),                             \
        slab_base(xT, n, idx[v * KK + 1], (TBP)),                             \
        slab_base(xT, n, idx[v * KK + 2], (TBP))};                            \
    _Pragma("unroll") for (int s = 0; s < KK; ++s) {                          \
      const char* gb = gbs[s];                                                \
      _Pragma("unroll") for (int q = 0; q < 4; ++q) {                         \
        int c = wave + q * 4;                                                 \
        int Lb = c * 1024 + lane * 16;                                        \
        int g = Lb ^ (((Lb >> 7) & 7) << 4);                                  \
        __builtin_amdgcn_global_load_lds(                                     \
            (const __attribute__((address_space(1))) void*)(gb + g),          \
            (__attribute__((address_space(3))) void*)(&xs[s][c * 1024]),      \
            16, 0, 0);                                                        \
      }                                                                       \
      if (wave == 0) {                                                        \
        int Lb = 16 * 1024 + lane * 16;                                       \
        int g = Lb ^ (((Lb >> 7) & 7) << 4);                                  \
        __builtin_amdgcn_global_load_lds(                                     \
            (const __attribute__((address_space(1))) void*)(gb + g),          \
            (__attribute__((address_space(3))) void*)(&xs[s][16 * 1024]),     \
            16, 0, 0);                                                        \
      } else {                                                                \
        __builtin_amdgcn_global_load_lds(                                     \
            (const __attribute__((address_space(1))) void*)(gb + lane * 16),  \
            (__attribute__((address_space(3))) void*)(xs_dummy),              \
            16, 0, 0);                                                        \
      }                                                                       \
      __builtin_amdgcn_sched_barrier(0);                                      \
    }                                                                         \
  }

#define COMPUTE_K(CB, A)                                                      \
  _Pragma("unroll") for (int kt = 0; kt < TKK; ++kt) {                        \
    {                                                                         \
      const int r  = th * 64 + l31 + kt;                                      \
      const int sw = (r & 7) << 4;                                            \
      const int co = hi * 16;                                                 \
      const char* bp = (CB) + r * 128;                                        \
      _Pragma("unroll") for (int ks = 0; ks < 4; ++ks) {                      \
        short8 bfr = *(const short8*)(bp + ((co + 32 * ks) ^ sw));            \
        acc0 = __builtin_amdgcn_mfma_f32_32x32x16_bf16(A[kt * 4 + ks], bfr,   \
                                                       acc0, 0, 0, 0);        \
      }                                                                       \
    }                                                                         \
    {                                                                         \
      const int r  = th * 64 + 32 + l31 + kt;                                 \
      const int sw = (r & 7) << 4;                                            \
      const int co = hi * 16;                                                 \
      const char* bp = (CB) + r * 128;                                        \
      _Pragma("unroll") for (int ks = 0; ks < 4; ++ks) {                      \
        short8 bfr = *(const short8*)(bp + ((co + 32 * ks) ^ sw));            \
        acc1 = __builtin_amdgcn_mfma_f32_32x32x16_bf16(A[kt * 4 + ks], bfr,   \
                                                       acc1, 0, 0, 0);        \
      }                                                                       \
    }                                                                         \
  }

#define STORES(PHB)                                                           \
  {                                                                           \
    const float* bv = bias + v * COUTC;                                       \
    _Pragma("unroll") for (int s = 0; s < 2; ++s) {                           \
      const f32x16& acc = s ? acc1 : acc0;                                    \
      const int t = (PHB) + th * 64 + s * 32 + l31;                           \
      _Pragma("unroll") for (int reg = 0; reg < 16; ++reg) {                  \
        int o = os * 32 + 4 * hi + (reg & 3) + 8 * (reg >> 2);                \
        out[(((size_t)n * COUTC + o) * NV + v) * TLEN + t] = acc[reg] + bv[o];\
      }                                                                       \
    }                                                                         \
  }

  const int tb0 = tc * 256;
  short8 aP[12], aQ[12];
  f32x16 acc0 = {}, acc1 = {};

  // ---- prologue: A0 (12, oldest), then phase-0 stages (15) ----
  LOAD_A(aP, 0)
  __builtin_amdgcn_sched_barrier(0);
  STAGE_PHASE(tb0)

  // ---- phase 0 ---- queue: A0(12)+s(15)=27
  asm volatile("s_waitcnt vmcnt(10)" ::: "memory");   // A0+s0 done
  __builtin_amdgcn_s_barrier();
  __builtin_amdgcn_sched_barrier(0);
  LOAD_A(aQ, 1)                                       // A1 under k0
  __builtin_amdgcn_sched_barrier(0);
  COMPUTE_K(xs[0], aP)

  asm volatile("s_waitcnt vmcnt(17)" ::: "memory");   // s1 done [s2+A1=17]
  __builtin_amdgcn_s_barrier();
  __builtin_amdgcn_sched_barrier(0);
  LOAD_A(aP, 2)                                       // A2 under k1
  __builtin_amdgcn_sched_barrier(0);
  COMPUTE_K(xs[1], aQ)

  asm volatile("s_waitcnt vmcnt(12)" ::: "memory");   // s2 done [A2=12]
  __builtin_amdgcn_s_barrier();
  __builtin_amdgcn_sched_barrier(0);
  COMPUTE_K(xs[2], aP)

  // ---- phase boundary: all phase-0 LDS reads done -> restage + store ----
  __builtin_amdgcn_s_barrier();
  __builtin_amdgcn_sched_barrier(0);
  LOAD_A(aQ, 0)                                       // A0' (L2-hot reload)
  __builtin_amdgcn_sched_barrier(0);
  STAGE_PHASE(tb0 + 128)
  __builtin_amdgcn_sched_barrier(0);
  STORES(tb0)                                         // 32 store ops behind
  __builtin_amdgcn_sched_barrier(0);
  acc0 = (f32x16){};
  acc1 = (f32x16){};

  // ---- phase 1 ---- queue: A0'(12)+s'(15)+st(32)=59
  asm volatile("s_waitcnt vmcnt(42)" ::: "memory");   // A0'+s0' done
  __builtin_amdgcn_s_barrier();
  __builtin_amdgcn_sched_barrier(0);
  LOAD_A(aP, 1)                                       // A1' under k0'
  __builtin_amdgcn_sched_barrier(0);
  COMPUTE_K(xs[0], aQ)

  asm volatile("s_waitcnt vmcnt(49)" ::: "memory");   // s1' done [s2'+st+A1'=49]
  __builtin_amdgcn_s_barrier();
  __builtin_amdgcn_sched_barrier(0);
  LOAD_A(aQ, 2)                                       // A2' under k1'
  __builtin_amdgcn_sched_barrier(0);
  COMPUTE_K(xs[1], aP)

  asm volatile("s_waitcnt vmcnt(12)" ::: "memory");   // s2'+st done [A2'=12]
  __builtin_amdgcn_s_barrier();
  __builtin_amdgcn_sched_barrier(0);
  COMPUTE_K(xs[2], aQ)

  STORES(tb0 + 128)

#undef LOAD_A
#undef STAGE_PHASE
#undef COMPUTE_K
#undef STORES
}

// ================= FALLBACK PATH (round-1 fp32, known-good) =================
__global__ void prep_mask_kernel(const int* __restrict__ mask_raw,
                                 int* __restrict__ mask_out) {
  __shared__ int fmt;
  if (threadIdx.x == 0) {
    int ok = 1;
    for (int i = 0; i < 18; ++i) {
      int m = mask_raw[i];
      if (m != 0 && m != 1) ok = 0;
    }
    fmt = ok;
  }
  __syncthreads();
  int i = threadIdx.x;
  if (i < NV * KK) {
    int m;
    if (fmt) m = mask_raw[i];
    else     m = (((const unsigned char*)mask_raw)[i] != 0) ? 1 : 0;
    mask_out[i] = m;
  }
}

__global__ void prep_wt_kernel(const float* __restrict__ W,
                               float* __restrict__ Wt) {
  int v   = blockIdx.x / 9;
  int kkt = blockIdx.x % 9;
  const float* Wv = W + (size_t)v * COUTC * CINC * 9;
  float* dst = Wt + (size_t)blockIdx.x * (CINC * COUTC);
  for (int i = threadIdx.x; i < CINC * COUTC; i += 256) {
    int c = i >> 6;
    int o = i & 63;
    dst[i] = Wv[(o * CINC + c) * 9 + kkt];
  }
}

__global__ __launch_bounds__(256, 4) void lcn_main(
    const float* __restrict__ x, const float* __restrict__ Wt,
    const float* __restrict__ b, const int* __restrict__ idx,
    const int* __restrict__ maskn, float* __restrict__ out) {
  __shared__ float xsf[CINC][66];
  __shared__ float wsh[CINC][COUTC];
  const int tb  = blockIdx.x * 64;
  const int v   = blockIdx.y;
  const int n   = blockIdx.z;
  const int tid = threadIdx.x;
  const int t0  = tid & 63;
  const int og  = tid >> 6;
  float acc[16];
#pragma unroll
  for (int j = 0; j < 16; ++j) acc[j] = 0.f;
  for (int k = 0; k < KK; ++k) {
    const int vk = idx[v * KK + k];
    const int mk = maskn[v * KK + k];
    __syncthreads();
    for (int i = tid; i < CINC * 66; i += 256) {
      int c  = i / 66;
      int tt = i - c * 66;
      int gt = tb - 1 + tt;
      float val = 0.f;
      if (mk && gt >= 0 && gt < TLEN)
        val = x[(((size_t)n * CINC + c) * NV + vk) * TLEN + gt];
      xsf[c][tt] = val;
    }
    for (int kt = 0; kt < TKK; ++kt) {
      __syncthreads();
      const float4* src =
          (const float4*)(Wt + ((size_t)(v * KK + k) * TKK + kt) * (CINC * COUTC));
      for (int i = tid; i < CINC * COUTC / 4; i += 256)
        ((float4*)wsh)[i] = src[i];
      __syncthreads();
#pragma unroll 4
      for (int c = 0; c < CINC; ++c) {
        float xv = xsf[c][t0 + kt];
        const float4* wrow = (const float4*)&wsh[c][og * 16];
#pragma unroll
        for (int j4 = 0; j4 < 4; ++j4) {
          float4 wv = wrow[j4];
          acc[j4 * 4 + 0] = fmaf(wv.x, xv, acc[j4 * 4 + 0]);
          acc[j4 * 4 + 1] = fmaf(wv.y, xv, acc[j4 * 4 + 1]);
          acc[j4 * 4 + 2] = fmaf(wv.z, xv, acc[j4 * 4 + 2]);
          acc[j4 * 4 + 3] = fmaf(wv.w, xv, acc[j4 * 4 + 3]);
        }
      }
    }
  }
#pragma unroll
  for (int j = 0; j < 16; ++j) {
    int o = og * 16 + j;
    out[(((size_t)n * COUTC + o) * NV + v) * TLEN + tb + t0] =
        acc[j] + b[v * COUTC + o];
  }
}

extern "C" void kernel_launch(void* const* d_in, const int* in_sizes, int n_in,
                              void* d_out, int out_size, void* d_ws, size_t ws_size,
                              hipStream_t stream) {
  const float* x    = (const float*)d_in[0];
  const float* W    = (const float*)d_in[1];
  const float* b    = (const float*)d_in[2];
  const int*   idx  = (const int*)d_in[3];
  const void*  mask = (const void*)d_in[4];
  float* out = (float*)d_out;

  // ws: [0,512) maskn (fallback) | Wt3 1.84MB | xT padded 26.3MB | guard
  const size_t WT3_BYTES = (size_t)NV * 9 * 4096 * sizeof(__hip_bfloat16);
  const size_t XT_BYTES  = (size_t)NB * NV * XT_ROWS * CINC * sizeof(__hip_bfloat16);
  const size_t NEED      = 512 + WT3_BYTES + XT_BYTES + 2048;

  if (ws_size >= NEED) {
    __hip_bfloat16* Wt3 = (__hip_bfloat16*)((char*)d_ws + 512);
    __hip_bfloat16* xT  = (__hip_bfloat16*)((char*)d_ws + 512 + WT3_BYTES);
    hipLaunchKernelGGL(prep_all, dim3(NWT3BLK + 8 * NV * NB), dim3(256), 0,
                       stream, x, W, (const unsigned char*)mask, Wt3, xT);
    hipLaunchKernelGGL(lcn_mfma32, dim3(NB * 2 * NV), dim3(256), 0,
                       stream, xT, Wt3, b, idx, out);
  } else {
    int*   maskn = (int*)d_ws;
    float* Wt    = (float*)((char*)d_ws + 512);
    hipLaunchKernelGGL(prep_mask_kernel, dim3(1), dim3(128), 0, stream,
                       (const int*)mask, maskn);
    hipLaunchKernelGGL(prep_wt_kernel, dim3(NV * KK * TKK), dim3(256), 0, stream,
                       W, Wt);
    hipLaunchKernelGGL(lcn_main, dim3(TLEN / 64, NV, NB), dim3(256), 0, stream,
                       x, Wt, b, idx, maskn, out);
  }
}

// Round 14
// 46.795 us; speedup vs baseline: 1.7742x; 1.7742x over previous
//
#include <hip/hip_runtime.h>
#include <hip/hip_bf16.h>

#define NB   16
#define CINC 64
#define COUTC 64
#define NV   25
#define TLEN 512
#define KK   3
#define TKK  3

typedef short short8 __attribute__((ext_vector_type(8)));
typedef float f32x4  __attribute__((ext_vector_type(4)));
typedef float f32x16 __attribute__((ext_vector_type(16)));

#define XT_ROWS 514        // padded: row 0 = t=-1 (zero), rows 1..512 = t, row 513 = t=512 (zero)
#define XS_STRIDE 17408    // 17 x 1KB stage ops; used bytes = 130*128 = 16640
#define NWT3BLK (NV * 9)   // 225 weight-prep blocks

__device__ __forceinline__ unsigned pack_bf16(float lo, float hi) {
  __hip_bfloat16 l = __float2bfloat16(lo);
  __hip_bfloat16 h = __float2bfloat16(hi);
  unsigned short ul = *reinterpret_cast<unsigned short*>(&l);
  unsigned short uh = *reinterpret_cast<unsigned short*>(&h);
  return (unsigned)ul | ((unsigned)uh << 16);
}

// ================= fused prep: Wt3 (blocks 0..224) + padded xT (rest) ========
__global__ __launch_bounds__(256) void prep_all(
    const float* __restrict__ x, const float* __restrict__ W,
    const unsigned char* __restrict__ mask_raw,
    __hip_bfloat16* __restrict__ Wt3, __hip_bfloat16* __restrict__ xT) {
  __shared__ float ts[64][65];
  int bid = blockIdx.x;
  if (bid < NWT3BLK) {
    int blk = bid;                 // v*9 + k*3 + kt
    int v = blk / 9, kkt = blk % 9, k = kkt / 3, kt = kkt % 3;
    const int* mi = (const int*)mask_raw;
    int ok = 1;
    for (int i = 0; i < 18; ++i) {
      int m = mi[i];
      if (m != 0 && m != 1) ok = 0;
    }
    int m = ok ? mi[v * KK + k] : (int)(mask_raw[v * KK + k] != 0);
    const float* Wv = W + (size_t)v * COUTC * CINC * 9;
    __hip_bfloat16* dst = Wt3 + (size_t)blk * 4096;
    for (int i = threadIdx.x; i < 4096; i += 256) {
      int e     = i & 7;
      int lane  = (i >> 3) & 63;
      int ks    = (i >> 9) & 3;
      int oslab = i >> 11;
      int o = oslab * 32 + (lane & 31);
      int c = ks * 16 + 8 * (lane >> 5) + e;
      float val = m ? Wv[(o * CINC + c) * 9 + k * 3 + kt] : 0.f;
      dst[i] = __float2bfloat16(val);
    }
    return;
  }
  bid -= NWT3BLK;
  const int tb = (bid & 7) * 64;
  const int vn = bid >> 3;
  const int v  = vn % NV;
  const int n  = vn / NV;
  const int tid = threadIdx.x;
  for (int i = tid; i < 1024; i += 256) {
    int c = i >> 4, tq = (i & 15) * 4;
    float4 val = *(const float4*)(x + (((size_t)n * CINC + c) * NV + v) * TLEN + tb + tq);
    ts[c][tq + 0] = val.x;
    ts[c][tq + 1] = val.y;
    ts[c][tq + 2] = val.z;
    ts[c][tq + 3] = val.w;
  }
  __syncthreads();
  unsigned* base = (unsigned*)(xT + ((size_t)(n * NV + v) * XT_ROWS) * CINC);
  for (int i = tid; i < 2048; i += 256) {
    int c2 = i & 31, t = i >> 5;
    base[(tb + 1 + t) * 32 + c2] = pack_bf16(ts[2 * c2][t], ts[2 * c2 + 1][t]);
  }
  if (tb == 0 && tid < 32) base[tid] = 0u;
  if (tb == TLEN - 64 && tid < 32) base[513 * 32 + tid] = 0u;
}

__device__ __forceinline__ const char* slab_base(const __hip_bfloat16* xT,
                                                 int n, int vk, int tb) {
  return (const char*)xT + ((size_t)(n * NV + vk) * XT_ROWS + tb) * 128;
}

// Main: R10 verified optimum (46.6 us total). Counted-vmcnt schedule, raw
// s_barrier, A-prefetch ladder, one 128-t phase per block, 1600 blocks.
// R11-R13 established: XCD swizzle, 2-phase amortization, deep store-in-queue
// ladders are all null or negative. Do not deepen the queue further.
__global__ __launch_bounds__(256, 3) void lcn_mfma32(
    const __hip_bfloat16* __restrict__ xT,
    const __hip_bfloat16* __restrict__ Wt3,
    const float* __restrict__ bias,
    const int* __restrict__ idx,
    float* __restrict__ out) {
  __shared__ char xs[KK][XS_STRIDE];   // 52,224 B
  __shared__ char xs_dummy[1024];      // dummy-op sink (never read)

  const int tb   = blockIdx.x * 128;
  const int n    = blockIdx.y;
  const int v    = blockIdx.z;
  const int tid  = threadIdx.x;
  const int lane = tid & 63;
  const int wave = tid >> 6;
  const int os   = wave & 1;     // this wave's o-slab
  const int th   = wave >> 1;    // this wave's 64-t half
  const int hi   = lane >> 5;
  const int l31  = lane & 31;

#define LOAD_A(DST, KIDX)                                                     \
  {                                                                           \
    const short8* wb = (const short8*)Wt3 +                                   \
        ((size_t)((v * KK + (KIDX)) * TKK) * 2 + os) * 256 + lane;            \
    _Pragma("unroll") for (int kt = 0; kt < TKK; ++kt)                        \
      _Pragma("unroll") for (int ks = 0; ks < 4; ++ks)                        \
        DST[kt * 4 + ks] = wb[kt * 512 + (ks << 6)];                          \
  }

#define COMPUTE_K(CB, A)                                                      \
  _Pragma("unroll") for (int kt = 0; kt < TKK; ++kt) {                        \
    {                                                                         \
      const int r  = th * 64 + l31 + kt;                                      \
      const int sw = (r & 7) << 4;                                            \
      const int co = hi * 16;                                                 \
      const char* bp = (CB) + r * 128;                                        \
      _Pragma("unroll") for (int ks = 0; ks < 4; ++ks) {                      \
        short8 bfr = *(const short8*)(bp + ((co + 32 * ks) ^ sw));            \
        acc0 = __builtin_amdgcn_mfma_f32_32x32x16_bf16(A[kt * 4 + ks], bfr,   \
                                                       acc0, 0, 0, 0);        \
      }                                                                       \
    }                                                                         \
    {                                                                         \
      const int r  = th * 64 + 32 + l31 + kt;                                 \
      const int sw = (r & 7) << 4;                                            \
      const int co = hi * 16;                                                 \
      const char* bp = (CB) + r * 128;                                        \
      _Pragma("unroll") for (int ks = 0; ks < 4; ++ks) {                      \
        short8 bfr = *(const short8*)(bp + ((co + 32 * ks) ^ sw));            \
        acc1 = __builtin_amdgcn_mfma_f32_32x32x16_bf16(A[kt * 4 + ks], bfr,   \
                                                       acc1, 0, 0, 0);        \
      }                                                                       \
    }                                                                         \
  }

  // ---- prologue: A0 first (oldest in vmcnt queue), then stages s0,s1,s2 ----
  short8 aP[12], aQ[12];
  LOAD_A(aP, 0)
  __builtin_amdgcn_sched_barrier(0);
  {
    const char* gb0 = slab_base(xT, n, idx[v * KK + 0], tb);
    const char* gb1 = slab_base(xT, n, idx[v * KK + 1], tb);
    const char* gb2 = slab_base(xT, n, idx[v * KK + 2], tb);
#pragma unroll
    for (int s = 0; s < KK; ++s) {
      const char* gb = (s == 0) ? gb0 : ((s == 1) ? gb1 : gb2);
#pragma unroll
      for (int q = 0; q < 4; ++q) {
        int c = wave + q * 4;                // c in 0..15
        int Lb = c * 1024 + lane * 16;
        int g = Lb ^ (((Lb >> 7) & 7) << 4); // involution within 128B rows
        __builtin_amdgcn_global_load_lds(
            (const __attribute__((address_space(1))) void*)(gb + g),
            (__attribute__((address_space(3))) void*)(&xs[s][c * 1024]),
            16, 0, 0);
      }
      if (wave == 0) {                       // tail op: bytes 16384..17407
        int Lb = 16 * 1024 + lane * 16;
        int g = Lb ^ (((Lb >> 7) & 7) << 4);
        __builtin_amdgcn_global_load_lds(
            (const __attribute__((address_space(1))) void*)(gb + g),
            (__attribute__((address_space(3))) void*)(&xs[s][16 * 1024]),
            16, 0, 0);
      } else {                               // dummy: uniform 5 ops/slab/wave
        __builtin_amdgcn_global_load_lds(
            (const __attribute__((address_space(1))) void*)(gb + lane * 16),
            (__attribute__((address_space(3))) void*)(xs_dummy),
            16, 0, 0);
      }
      __builtin_amdgcn_sched_barrier(0);
    }
  }

  f32x16 acc0 = {}, acc1 = {};

  // ---- k = 0: wait own s0 (5 of 15 stage ops + A0 oldest) ----
  asm volatile("s_waitcnt vmcnt(10)" ::: "memory");
  __builtin_amdgcn_s_barrier();
  __builtin_amdgcn_sched_barrier(0);
  LOAD_A(aQ, 1)                              // prefetch A1 under k0 compute
  COMPUTE_K(xs[0], aP)

  // ---- k = 1: need s1; in-flight <= s2(5) + A1(12) ----
  asm volatile("s_waitcnt vmcnt(17)" ::: "memory");
  __builtin_amdgcn_s_barrier();
  __builtin_amdgcn_sched_barrier(0);
  COMPUTE_K(xs[1], aQ)

  // ---- k = 2: need s2; in-flight <= A1 leftovers (12) ----
  asm volatile("s_waitcnt vmcnt(12)" ::: "memory");
  __builtin_amdgcn_s_barrier();
  __builtin_amdgcn_sched_barrier(0);
  LOAD_A(aP, 2)                              // reuse aP (k0 MFMAs long done)
  COMPUTE_K(xs[2], aP)

#undef LOAD_A
#undef COMPUTE_K

  // epilogue: D col(t)=lane&31, row(o)=(reg&3)+8*(reg>>2)+4*(lane>>5)
  const float* bv = bias + v * COUTC;
#pragma unroll
  for (int s = 0; s < 2; ++s) {
    const f32x16& acc = s ? acc1 : acc0;
    const int t = tb + th * 64 + s * 32 + l31;
#pragma unroll
    for (int reg = 0; reg < 16; ++reg) {
      int o = os * 32 + 4 * hi + (reg & 3) + 8 * (reg >> 2);
      out[(((size_t)n * COUTC + o) * NV + v) * TLEN + t] = acc[reg] + bv[o];
    }
  }
}

// ================= FALLBACK PATH (round-1 fp32, known-good) =================
__global__ void prep_mask_kernel(const int* __restrict__ mask_raw,
                                 int* __restrict__ mask_out) {
  __shared__ int fmt;
  if (threadIdx.x == 0) {
    int ok = 1;
    for (int i = 0; i < 18; ++i) {
      int m = mask_raw[i];
      if (m != 0 && m != 1) ok = 0;
    }
    fmt = ok;
  }
  __syncthreads();
  int i = threadIdx.x;
  if (i < NV * KK) {
    int m;
    if (fmt) m = mask_raw[i];
    else     m = (((const unsigned char*)mask_raw)[i] != 0) ? 1 : 0;
    mask_out[i] = m;
  }
}

__global__ void prep_wt_kernel(const float* __restrict__ W,
                               float* __restrict__ Wt) {
  int v   = blockIdx.x / 9;
  int kkt = blockIdx.x % 9;
  const float* Wv = W + (size_t)v * COUTC * CINC * 9;
  float* dst = Wt + (size_t)blockIdx.x * (CINC * COUTC);
  for (int i = threadIdx.x; i < CINC * COUTC; i += 256) {
    int c = i >> 6;
    int o = i & 63;
    dst[i] = Wv[(o * CINC + c) * 9 + kkt];
  }
}

__global__ __launch_bounds__(256, 4) void lcn_main(
    const float* __restrict__ x, const float* __restrict__ Wt,
    const float* __restrict__ b, const int* __restrict__ idx,
    const int* __restrict__ maskn, float* __restrict__ out) {
  __shared__ float xsf[CINC][66];
  __shared__ float wsh[CINC][COUTC];
  const int tb  = blockIdx.x * 64;
  const int v   = blockIdx.y;
  const int n   = blockIdx.z;
  const int tid = threadIdx.x;
  const int t0  = tid & 63;
  const int og  = tid >> 6;
  float acc[16];
#pragma unroll
  for (int j = 0; j < 16; ++j) acc[j] = 0.f;
  for (int k = 0; k < KK; ++k) {
    const int vk = idx[v * KK + k];
    const int mk = maskn[v * KK + k];
    __syncthreads();
    for (int i = tid; i < CINC * 66; i += 256) {
      int c  = i / 66;
      int tt = i - c * 66;
      int gt = tb - 1 + tt;
      float val = 0.f;
      if (mk && gt >= 0 && gt < TLEN)
        val = x[(((size_t)n * CINC + c) * NV + vk) * TLEN + gt];
      xsf[c][tt] = val;
    }
    for (int kt = 0; kt < TKK; ++kt) {
      __syncthreads();
      const float4* src =
          (const float4*)(Wt + ((size_t)(v * KK + k) * TKK + kt) * (CINC * COUTC));
      for (int i = tid; i < CINC * COUTC / 4; i += 256)
        ((float4*)wsh)[i] = src[i];
      __syncthreads();
#pragma unroll 4
      for (int c = 0; c < CINC; ++c) {
        float xv = xsf[c][t0 + kt];
        const float4* wrow = (const float4*)&wsh[c][og * 16];
#pragma unroll
        for (int j4 = 0; j4 < 4; ++j4) {
          float4 wv = wrow[j4];
          acc[j4 * 4 + 0] = fmaf(wv.x, xv, acc[j4 * 4 + 0]);
          acc[j4 * 4 + 1] = fmaf(wv.y, xv, acc[j4 * 4 + 1]);
          acc[j4 * 4 + 2] = fmaf(wv.z, xv, acc[j4 * 4 + 2]);
          acc[j4 * 4 + 3] = fmaf(wv.w, xv, acc[j4 * 4 + 3]);
        }
      }
    }
  }
#pragma unroll
  for (int j = 0; j < 16; ++j) {
    int o = og * 16 + j;
    out[(((size_t)n * COUTC + o) * NV + v) * TLEN + tb + t0] =
        acc[j] + b[v * COUTC + o];
  }
}

extern "C" void kernel_launch(void* const* d_in, const int* in_sizes, int n_in,
                              void* d_out, int out_size, void* d_ws, size_t ws_size,
                              hipStream_t stream) {
  const float* x    = (const float*)d_in[0];
  const float* W    = (const float*)d_in[1];
  const float* b    = (const float*)d_in[2];
  const int*   idx  = (const int*)d_in[3];
  const void*  mask = (const void*)d_in[4];
  float* out = (float*)d_out;

  // ws: [0,512) maskn (fallback) | Wt3 1.84MB | xT padded 26.3MB | guard
  const size_t WT3_BYTES = (size_t)NV * 9 * 4096 * sizeof(__hip_bfloat16);
  const size_t XT_BYTES  = (size_t)NB * NV * XT_ROWS * CINC * sizeof(__hip_bfloat16);
  const size_t NEED      = 512 + WT3_BYTES + XT_BYTES + 2048;

  if (ws_size >= NEED) {
    __hip_bfloat16* Wt3 = (__hip_bfloat16*)((char*)d_ws + 512);
    __hip_bfloat16* xT  = (__hip_bfloat16*)((char*)d_ws + 512 + WT3_BYTES);
    hipLaunchKernelGGL(prep_all, dim3(NWT3BLK + 8 * NV * NB), dim3(256), 0,
                       stream, x, W, (const unsigned char*)mask, Wt3, xT);
    hipLaunchKernelGGL(lcn_mfma32, dim3(TLEN / 128, NB, NV), dim3(256), 0,
                       stream, xT, Wt3, b, idx, out);
  } else {
    int*   maskn = (int*)d_ws;
    float* Wt    = (float*)((char*)d_ws + 512);
    hipLaunchKernelGGL(prep_mask_kernel, dim3(1), dim3(128), 0, stream,
                       (const int*)mask, maskn);
    hipLaunchKernelGGL(prep_wt_kernel, dim3(NV * KK * TKK), dim3(256), 0, stream,
                       W, Wt);
    hipLaunchKernelGGL(lcn_main, dim3(TLEN / 64, NV, NB), dim3(256), 0, stream,
                       x, Wt, b, idx, maskn, out);
  }
}